// Round 5
// baseline (381.732 us; speedup 1.0000x reference)
//
#include <hip/hip_runtime.h>
#include <math.h>

#define B_   16
#define O_   1024
#define M_   64
#define C_   32
#define INO  16
#define INA  8
#define SLOPE 0.2f

// Accumulator field layout per column (col = (br*B_+b)*M_+m):
// IN  half: [0]=l_in,  [1..8]=ai,  [9..24]=aoi
// OUT half: [25]=l_out,[26..33]=sao,[34..49]=aoo
#define NF    50
#define NFH   25
#define NCOL  (2*B_*M_)   // 2048 columns

// workspace layout (float offsets)
#define WS_EOPE   0
#define WS_ENODE  (WS_EOPE + B_*O_)              // 16384
#define WS_PNODE  (WS_ENODE + 2*B_*M_)           // 18432
#define WS_WARC   (WS_PNODE + 2*B_*M_*C_)        // 83968
#define WS_ACC    (WS_WARC + 16)                 // 83984  (NF*NCOL = 102400 floats)

__device__ inline float rfl(float x) {
    return __int_as_float(__builtin_amdgcn_readfirstlane(__float_as_int(x)));
}

// ---------------- kernel 0: tiny precompute + ACC zeroing ----------------
__global__ void k_pre(const float* __restrict__ feat_opes,
                      const float* __restrict__ feat_mas,
                      const float* __restrict__ feat_buf,
                      const float* __restrict__ W_ope,
                      const float* __restrict__ W_mas,
                      const float* __restrict__ W_buf,
                      const float* __restrict__ W_arc_in,
                      const float* __restrict__ W_arc_out,
                      const float* __restrict__ attn_ope,
                      const float* __restrict__ attn_mas,
                      const float* __restrict__ attn_arc,
                      float* __restrict__ ws) {
    int tid = threadIdx.x;
    int bid = blockIdx.x;
    if (bid < 64) {
        __shared__ float wo[INO];
        if (tid < INO) {
            float s = 0.f;
            for (int c = 0; c < C_; ++c) s += W_ope[tid*C_ + c]*attn_ope[c];
            wo[tid] = s;
        }
        __syncthreads();
        int idx = bid*256 + tid;                 // [0, 16384)
        const float* f = feat_opes + idx*INO;
        float s = 0.f;
#pragma unroll
        for (int j = 0; j < INO; ++j) s += f[j]*wo[j];
        ws[WS_EOPE + idx] = s;
    } else if (bid < 72) {
        int idx = (bid - 64)*256 + tid;          // [0, 2048)
        int br  = idx >> 10;
        int rem = idx & 1023;
        const float* f = (br == 0 ? feat_mas : feat_buf) + rem*INA;
        const float* W = (br == 0 ? W_mas : W_buf);
        float f8[INA];
#pragma unroll
        for (int k = 0; k < INA; ++k) f8[k] = f[k];
        float e = 0.f;
        float* pn = ws + WS_PNODE + idx*C_;
        for (int c = 0; c < C_; ++c) {
            float s = 0.f;
#pragma unroll
            for (int k = 0; k < INA; ++k) s += f8[k]*W[k*C_ + c];
            pn[c] = s;
            e += s*attn_mas[c];
        }
        ws[WS_ENODE + idx] = e;
    } else if (bid == 72) {
        if (tid < 16) {
            const float* W = (tid < 8) ? W_arc_in : W_arc_out;
            int k = tid & 7;
            float s = 0.f;
            for (int c = 0; c < C_; ++c) s += W[k*C_ + c]*attn_arc[c];
            ws[WS_WARC + tid] = s;
        }
    } else {
        int idx = (bid - 73)*256 + tid;
        ws[WS_ACC + idx] = 0.f;
    }
}

// ---------------- kernel A: main streaming pass ----------------
// 256 threads = 4 waves: wave w -> stream = w>>1 (IN/OUT), q = w&1 (m-half).
// Lane l -> m = q*32 + (l>>1), h = l&1 selects which 16B half of the 32B
// (o,m) record this lane owns: ONE dwordx4 per iteration is a fully dense
// contiguous 1KB wave transaction (vs 50%-dense stride-32 before).
// Accumulators split by h: 13 live floats/lane -> no spill pressure.
__global__ __launch_bounds__(256, 6) void k_main(
        const float* __restrict__ adj0, const float* __restrict__ adj1,
        const float* __restrict__ adj2, const float* __restrict__ adj3,
        const float* __restrict__ feat_opes,
        const float* __restrict__ fin_ma,  const float* __restrict__ fin_buf,
        const float* __restrict__ fout_ma, const float* __restrict__ fout_buf,
        const float* __restrict__ ws_ro,
        float* __restrict__ acc) {
    int tid = threadIdx.x;
    int l  = tid & 63;
    int w  = __builtin_amdgcn_readfirstlane(tid >> 6);   // 0..3
    int s_ = w >> 1;             // 0 = IN, 1 = OUT
    int q  = w & 1;              // m-half
    int h  = l & 1;              // record half
    int m  = q*32 + (l >> 1);    // machine index 0..63
    int bid = blockIdx.x;
    int chunk = bid & 31;        // 32 chunks of 32 o's
    int t = bid >> 5;
    int b  = t & (B_ - 1);
    int br = t >> 4;
    int o0 = chunk*32;

    const float* A = s_ ? (br ? adj3 : adj1) : (br ? adj2 : adj0);
    const float* F = s_ ? (br ? fout_buf : fout_ma) : (br ? fin_buf : fin_ma);

    // per-lane 4-weight slice of the stream's 8-vector
    float4 wsel = *(const float4*)(ws_ro + WS_WARC + s_*8 + h*4);

    float e_node_m = ws_ro[WS_ENODE + (br*B_ + b)*M_ + m];

    // wave-uniform e_ope for the 32 o's -> SGPRs
    const float* eop = ws_ro + WS_EOPE + b*O_ + o0;
    float eo[32];
#pragma unroll
    for (int i = 0; i < 32; ++i) eo[i] = rfl(eop[i]);

    // adjacency -> 32-bit mask (1 VGPR)
    const float* Ap = A + o0*M_ + m;
    unsigned amask = 0;
#pragma unroll
    for (int i = 0; i < 32; ++i) amask |= (Ap[i*M_] == 1.0f) ? (1u << i) : 0u;

    // dense arc pointer: lane covers bytes [h*16, h*16+16) of record (o,m)
    const float* P  = F + ((size_t)(b*O_ + o0)*M_ + m)*INA + h*4;
    const float* fo = feat_opes + (size_t)(b*O_ + o0)*INO + h*8;
    const int OSTR = M_*INA;     // 512 floats per o

    float accl = 0.f;
    float a4x = 0.f, a4y = 0.f, a4z = 0.f, a4w = 0.f;
    float a16h[8];
#pragma unroll
    for (int j = 0; j < 8; ++j) a16h[j] = 0.f;

#pragma unroll
    for (int it = 0; it < 32; ++it) {
        float4 x  = *(const float4*)(P + (size_t)it*OSTR);
        float4 f0 = *(const float4*)(fo + it*INO);
        float4 f1 = *(const float4*)(fo + it*INO + 4);
        float p = x.x*wsel.x + x.y*wsel.y + x.z*wsel.z + x.w*wsel.w;
        float d = p + __shfl_xor(p, 1, 64);          // pair-sum -> full 8-dot
        float sc = eo[it] + e_node_m + d;
        sc = sc > 0.f ? sc : SLOPE*sc;
        float we = (amask & (1u << it)) ? __expf(sc) : 0.f;  // scores bounded
        accl += we;
        float g = s_ ? 1.0f : we;    // OUT stream: raw (unweighted) arc sum
        a4x += g*x.x; a4y += g*x.y; a4z += g*x.z; a4w += g*x.w;
        a16h[0] += we*f0.x; a16h[1] += we*f0.y; a16h[2] += we*f0.z; a16h[3] += we*f0.w;
        a16h[4] += we*f1.x; a16h[5] += we*f1.y; a16h[6] += we*f1.z; a16h[7] += we*f1.w;
    }

    // ---- block reduction: each (field, m) written by exactly one lane ----
    __shared__ float red[2][NFH][64];
    if (h == 0) {
        red[s_][0][m] = accl;        // both pair-lanes hold identical accl
        red[s_][1][m] = a4x; red[s_][2][m] = a4y;
        red[s_][3][m] = a4z; red[s_][4][m] = a4w;
#pragma unroll
        for (int j = 0; j < 8; ++j) red[s_][9+j][m] = a16h[j];
    } else {
        red[s_][5][m] = a4x; red[s_][6][m] = a4y;
        red[s_][7][m] = a4z; red[s_][8][m] = a4w;
#pragma unroll
        for (int j = 0; j < 8; ++j) red[s_][17+j][m] = a16h[j];
    }
    __syncthreads();

    // flat coalesced atomic push: 2*25*64 = 3200 values
    int colbase = (br*B_ + b)*M_;
    for (int i = tid; i < 2*NFH*64; i += 256) {
        int s2 = i >> 10;            // /1600 -> use power-of-2 split instead:
        // decompose: i = s2*1600 + f*64 + m2  (1600 not pow2 -> do it manually)
        int r  = i - ((i >= 1600) ? 1600 : 0);
        s2 = (i >= 1600) ? 1 : 0;
        int f  = r >> 6;
        int m2 = r & 63;
        unsafeAtomicAdd(acc + (s2*NFH + f)*NCOL + colbase + m2, red[s2][f][m2]);
    }
}

// ---------------- kernel B: epilogue ----------------
__global__ __launch_bounds__(64) void k_fin(
        const float* __restrict__ W_ope,
        const float* __restrict__ W_arc_in,
        const float* __restrict__ W_arc_out,
        const float* __restrict__ ws,
        float* __restrict__ out) {
    int m = threadIdx.x;         // [0,64)
    int bid = blockIdx.x;        // [0,32)
    int b  = bid & (B_ - 1);
    int br = bid >> 4;
    int col = (br*B_ + b)*M_ + m;

    __shared__ float sW[1024];
    for (int i = m; i < 512; i += 64) sW[i] = W_ope[i];
    for (int i = m; i < 256; i += 64) { sW[512 + i] = W_arc_in[i]; sW[768 + i] = W_arc_out[i]; }
    __syncthreads();

    const float* acc = ws + WS_ACC;
    float v[NF];
#pragma unroll
    for (int f = 0; f < NF; ++f) v[f] = acc[f*NCOL + col];

    const float* pn = ws + WS_PNODE + col*C_;
    float pc[C_];
#pragma unroll
    for (int q = 0; q < 8; ++q) {
        float4 p4 = *(const float4*)(pn + 4*q);
        pc[4*q] = p4.x; pc[4*q+1] = p4.y; pc[4*q+2] = p4.z; pc[4*q+3] = p4.w;
    }

    float en  = ws[WS_ENODE + col];
    float ekk = 2.f*en; ekk = ekk > 0.f ? ekk : SLOPE*ekk;
    float wkk = __expf(ekk);

    float inv_i = 1.f / (v[0]  + wkk);
    float inv_o = 1.f / (v[25] + wkk);
    float akk   = wkk*inv_i + wkk*inv_o;

    float* op = out + (size_t)col*C_;
#pragma unroll 4
    for (int c = 0; c < C_; ++c) {
        float s_ai = 0.f, s_oi = 0.f, s_ao = 0.f, s_oo = 0.f;
#pragma unroll
        for (int k = 0; k < 8; ++k) {
            s_ai += v[1+k] *sW[512 + k*C_ + c];
            s_ao += v[26+k]*sW[768 + k*C_ + c];
        }
#pragma unroll
        for (int j = 0; j < 16; ++j) {
            float wv = sW[j*C_ + c];
            s_oi += v[9+j] *wv;
            s_oo += v[34+j]*wv;
        }
        float x = (s_ai + s_oi)*inv_i + s_ao + s_oo*inv_o + pc[c]*akk;
        op[c] = 1.f/(1.f + __expf(-x));
    }
}

extern "C" void kernel_launch(void* const* d_in, const int* in_sizes, int n_in,
                              void* d_out, int out_size, void* d_ws, size_t ws_size,
                              hipStream_t stream) {
    const float* adj0 = (const float*)d_in[0];
    const float* adj1 = (const float*)d_in[1];
    const float* adj2 = (const float*)d_in[2];
    const float* adj3 = (const float*)d_in[3];
    // d_in[4] = batch_idxes (unused by the reference)
    const float* feat_opes       = (const float*)d_in[5];
    const float* feat_mas        = (const float*)d_in[6];
    const float* feat_buf        = (const float*)d_in[7];
    const float* feat_arc_ma_in  = (const float*)d_in[8];
    const float* feat_arc_buf_in = (const float*)d_in[9];
    const float* feat_arc_ma_out = (const float*)d_in[10];
    const float* feat_arc_buf_out= (const float*)d_in[11];
    const float* W_ope    = (const float*)d_in[12];
    const float* W_mas    = (const float*)d_in[13];
    const float* W_buf    = (const float*)d_in[14];
    const float* W_arc_in = (const float*)d_in[15];
    const float* W_arc_out= (const float*)d_in[16];
    const float* attn_ope = (const float*)d_in[17];
    const float* attn_mas = (const float*)d_in[18];
    const float* attn_arc = (const float*)d_in[19];

    float* ws  = (float*)d_ws;
    float* out = (float*)d_out;

    k_pre<<<473, 256, 0, stream>>>(feat_opes, feat_mas, feat_buf,
                                   W_ope, W_mas, W_buf, W_arc_in, W_arc_out,
                                   attn_ope, attn_mas, attn_arc, ws);

    // 1024 blocks x 256 threads; wave = (stream, m-half), 32 o's per wave
    k_main<<<2*B_*32, 256, 0, stream>>>(adj0, adj1, adj2, adj3, feat_opes,
                                        feat_arc_ma_in, feat_arc_buf_in,
                                        feat_arc_ma_out, feat_arc_buf_out,
                                        ws, ws + WS_ACC);

    k_fin<<<2*B_, 64, 0, stream>>>(W_ope, W_arc_in, W_arc_out, ws, out);
}

// Round 6
// 209.221 us; speedup vs baseline: 1.8245x; 1.8245x over previous
//
#include <hip/hip_runtime.h>
#include <math.h>

#define B_   16
#define O_   1024
#define M_   64
#define C_   32
#define INO  16
#define INA  8
#define S_CH 32          // o-chunks (of 32 o's) per (b,branch)
#define SLOPE 0.2f

// Accumulator field layout per column (col = (br*B_+b)*M_+m):
// [0]=l_in, [1..8]=ai, [9..24]=aoi, [25]=l_out, [26..41]=aoo, [42..49]=sao
#define NF    50
#define NCOL  (2*B_*M_)   // 2048 columns

// workspace layout (float offsets)
#define WS_EOPE   0
#define WS_ENODE  (WS_EOPE + B_*O_)              // 16384
#define WS_PNODE  (WS_ENODE + 2*B_*M_)           // 18432
#define WS_WARC   (WS_PNODE + 2*B_*M_*C_)        // 83968
#define WS_ACC    (WS_WARC + 16)                 // 83984  (NF*NCOL = 102400 floats)

__device__ inline float rfl(float x) {
    return __int_as_float(__builtin_amdgcn_readfirstlane(__float_as_int(x)));
}

// ---------------- kernel 0: tiny precompute + ACC zeroing ----------------
__global__ void k_pre(const float* __restrict__ feat_opes,
                      const float* __restrict__ feat_mas,
                      const float* __restrict__ feat_buf,
                      const float* __restrict__ W_ope,
                      const float* __restrict__ W_mas,
                      const float* __restrict__ W_buf,
                      const float* __restrict__ W_arc_in,
                      const float* __restrict__ W_arc_out,
                      const float* __restrict__ attn_ope,
                      const float* __restrict__ attn_mas,
                      const float* __restrict__ attn_arc,
                      float* __restrict__ ws) {
    int tid = threadIdx.x;
    int bid = blockIdx.x;
    if (bid < 64) {
        // e_ope[b,o] = feat_opes[b,o,:] . (W_ope @ attn_ope)
        __shared__ float wo[INO];
        if (tid < INO) {
            float s = 0.f;
            for (int c = 0; c < C_; ++c) s += W_ope[tid*C_ + c]*attn_ope[c];
            wo[tid] = s;
        }
        __syncthreads();
        int idx = bid*256 + tid;                 // [0, 16384)
        const float* f = feat_opes + idx*INO;
        float s = 0.f;
#pragma unroll
        for (int j = 0; j < INO; ++j) s += f[j]*wo[j];
        ws[WS_EOPE + idx] = s;
    } else if (bid < 72) {
        // p_node / e_node for both branches
        int idx = (bid - 64)*256 + tid;          // [0, 2048)
        int br  = idx >> 10;
        int rem = idx & 1023;
        const float* f = (br == 0 ? feat_mas : feat_buf) + rem*INA;
        const float* W = (br == 0 ? W_mas : W_buf);
        float f8[INA];
#pragma unroll
        for (int k = 0; k < INA; ++k) f8[k] = f[k];
        float e = 0.f;
        float* pn = ws + WS_PNODE + idx*C_;
        for (int c = 0; c < C_; ++c) {
            float s = 0.f;
#pragma unroll
            for (int k = 0; k < INA; ++k) s += f8[k]*W[k*C_ + c];
            pn[c] = s;
            e += s*attn_mas[c];
        }
        ws[WS_ENODE + idx] = e;
    } else if (bid == 72) {
        // w_arc_in/out 8-vectors: W_arc @ attn_arc
        if (tid < 16) {
            const float* W = (tid < 8) ? W_arc_in : W_arc_out;
            int k = tid & 7;
            float s = 0.f;
            for (int c = 0; c < C_; ++c) s += W[k*C_ + c]*attn_arc[c];
            ws[WS_WARC + tid] = s;
        }
    } else {
        // zero the atomic accumulator region (NF*NCOL = 102400 floats, 400 blocks)
        int idx = (bid - 73)*256 + tid;
        ws[WS_ACC + idx] = 0.f;
    }
}

// ---------------- kernel A: main streaming pass ----------------
// Exact R2 structure (the only proven-clean config: bare launch_bounds(256),
// VGPR 92, WRITE=atomics-only) with ONE change: a 4-deep rotating register
// buffer for the arc loads so ~16 wave-instructions are in flight instead of
// ~4. Wave-uniform weights/e_ope moved to SGPRs (readfirstlane) to pay for
// the 64 data VGPRs. NO second launch_bounds arg — it has poisoned the
// allocator into spilling in rounds 3,4,5.
__global__ __launch_bounds__(256) void k_main(
        const float* __restrict__ adj0, const float* __restrict__ adj1,
        const float* __restrict__ adj2, const float* __restrict__ adj3,
        const float* __restrict__ feat_opes,
        const float* __restrict__ fin_ma,  const float* __restrict__ fin_buf,
        const float* __restrict__ fout_ma, const float* __restrict__ fout_buf,
        float* __restrict__ ws) {
    int tid = threadIdx.x;
    int m = tid & 63;
    int y = __builtin_amdgcn_readfirstlane(tid >> 6);
    int bid = blockIdx.x;
    int chunk = bid & (S_CH - 1);
    int t = bid >> 5;            // log2(S_CH)
    int b = t & (B_ - 1);
    int br = t >> 4;

    const float* A_in  = br ? adj2 : adj0;
    const float* A_out = br ? adj3 : adj1;
    const float* fin   = br ? fin_buf  : fin_ma;
    const float* fout  = br ? fout_buf : fout_ma;

    int o0 = chunk*32 + y*8;     // this wave handles o in [o0, o0+8)

    float e_node_m = ws[WS_ENODE + (br*B_ + b)*M_ + m];

    // wave-uniform weight vectors -> SGPRs
    const float* wv = ws + WS_WARC;
    float w_in0=rfl(wv[0]),w_in1=rfl(wv[1]),w_in2=rfl(wv[2]),w_in3=rfl(wv[3]);
    float w_in4=rfl(wv[4]),w_in5=rfl(wv[5]),w_in6=rfl(wv[6]),w_in7=rfl(wv[7]);
    float w_ot0=rfl(wv[8]),w_ot1=rfl(wv[9]),w_ot2=rfl(wv[10]),w_ot3=rfl(wv[11]);
    float w_ot4=rfl(wv[12]),w_ot5=rfl(wv[13]),w_ot6=rfl(wv[14]),w_ot7=rfl(wv[15]);

    // wave-uniform e_ope -> SGPRs
    const float* e_ope = ws + WS_EOPE + b*O_ + o0;
    float eo[8];
#pragma unroll
    for (int i = 0; i < 8; ++i) eo[i] = rfl(e_ope[i]);

    // per-lane adjacency -> bitmask (2 VGPRs)
    const float* Ai = A_in  + o0*M_ + m;
    const float* Ao = A_out + o0*M_ + m;
    unsigned amA = 0, amB = 0;
#pragma unroll
    for (int i = 0; i < 8; ++i) {
        amA |= (Ai[i*M_] == 1.0f) ? (1u << i) : 0u;
        amB |= (Ao[i*M_] == 1.0f) ? (1u << i) : 0u;
    }

    const float* pi = fin  + ((size_t)(b*O_ + o0)*M_ + m)*INA;
    const float* po = fout + ((size_t)(b*O_ + o0)*M_ + m)*INA;
    const int OSTR = M_*INA;     // 512 floats per o

    float ai[8], sao[8], wiv[8], wov[8];
#pragma unroll
    for (int k = 0; k < 8; ++k) { ai[k] = 0.f; sao[k] = 0.f; }

    // 4-deep rotating load pipeline: 16 dwordx4 in flight
    float4 bi0[4], bi1[4], bu0[4], bu1[4];
#pragma unroll
    for (int p = 0; p < 4; ++p) {
        bi0[p] = *(const float4*)(pi + p*OSTR);
        bi1[p] = *(const float4*)(pi + p*OSTR + 4);
        bu0[p] = *(const float4*)(po + p*OSTR);
        bu1[p] = *(const float4*)(po + p*OSTR + 4);
    }

#pragma unroll
    for (int it = 0; it < 8; ++it) {
        const int sl = it & 3;
        float4 i0 = bi0[sl], i1 = bi1[sl], u0 = bu0[sl], u1 = bu1[sl];
        if (it + 4 < 8) {
            bi0[sl] = *(const float4*)(pi + (it+4)*OSTR);
            bi1[sl] = *(const float4*)(pi + (it+4)*OSTR + 4);
            bu0[sl] = *(const float4*)(po + (it+4)*OSTR);
            bu1[sl] = *(const float4*)(po + (it+4)*OSTR + 4);
        }
        float ein = i0.x*w_in0 + i0.y*w_in1 + i0.z*w_in2 + i0.w*w_in3
                  + i1.x*w_in4 + i1.y*w_in5 + i1.z*w_in6 + i1.w*w_in7;
        float eut = u0.x*w_ot0 + u0.y*w_ot1 + u0.z*w_ot2 + u0.w*w_ot3
                  + u1.x*w_ot4 + u1.y*w_ot5 + u1.z*w_ot6 + u1.w*w_ot7;
        float base = eo[it] + e_node_m;
        float si = base + ein;  si = si > 0.f ? si : SLOPE*si;
        float so = base + eut;  so = so > 0.f ? so : SLOPE*so;
        // scores bounded for this data -> plain exp, no max-subtraction
        float wi  = (amA & (1u << it)) ? __expf(si) : 0.f;
        float wo_ = (amB & (1u << it)) ? __expf(so) : 0.f;
        wiv[it] = wi; wov[it] = wo_;
        ai[0] += wi*i0.x; ai[1] += wi*i0.y; ai[2] += wi*i0.z; ai[3] += wi*i0.w;
        ai[4] += wi*i1.x; ai[5] += wi*i1.y; ai[6] += wi*i1.z; ai[7] += wi*i1.w;
        sao[0] += u0.x; sao[1] += u0.y; sao[2] += u0.z; sao[3] += u0.w;
        sao[4] += u1.x; sao[5] += u1.y; sao[6] += u1.z; sao[7] += u1.w;
    }

    float l_in = 0.f, l_out = 0.f;
#pragma unroll
    for (int it = 0; it < 8; ++it) { l_in += wiv[it]; l_out += wov[it]; }

    // deferred feat_opes-weighted sums (wave-uniform rows, off critical path)
    float aoi[16], aoo[16];
#pragma unroll
    for (int j = 0; j < 16; ++j) { aoi[j] = 0.f; aoo[j] = 0.f; }
    const float* fo_base = feat_opes + (size_t)(b*O_ + o0)*INO;
#pragma unroll
    for (int it = 0; it < 8; ++it) {
        const float4* fp = (const float4*)(fo_base + it*INO);
        float4 f0 = fp[0], f1 = fp[1], f2 = fp[2], f3 = fp[3];
        float wi = wiv[it], wo_ = wov[it];
        aoi[0]  += wi*f0.x; aoi[1]  += wi*f0.y; aoi[2]  += wi*f0.z; aoi[3]  += wi*f0.w;
        aoi[4]  += wi*f1.x; aoi[5]  += wi*f1.y; aoi[6]  += wi*f1.z; aoi[7]  += wi*f1.w;
        aoi[8]  += wi*f2.x; aoi[9]  += wi*f2.y; aoi[10] += wi*f2.z; aoi[11] += wi*f2.w;
        aoi[12] += wi*f3.x; aoi[13] += wi*f3.y; aoi[14] += wi*f3.z; aoi[15] += wi*f3.w;
        aoo[0]  += wo_*f0.x; aoo[1]  += wo_*f0.y; aoo[2]  += wo_*f0.z; aoo[3]  += wo_*f0.w;
        aoo[4]  += wo_*f1.x; aoo[5]  += wo_*f1.y; aoo[6]  += wo_*f1.z; aoo[7]  += wo_*f1.w;
        aoo[8]  += wo_*f2.x; aoo[9]  += wo_*f2.y; aoo[10] += wo_*f2.z; aoo[11] += wo_*f2.w;
        aoo[12] += wo_*f3.x; aoo[13] += wo_*f3.y; aoo[14] += wo_*f3.z; aoo[15] += wo_*f3.w;
    }

    // pack state vector
    float v[NF];
    v[0] = l_in;
#pragma unroll
    for (int k = 0; k < 8; ++k)  v[1+k]  = ai[k];
#pragma unroll
    for (int j = 0; j < 16; ++j) v[9+j]  = aoi[j];
    v[25] = l_out;
#pragma unroll
    for (int j = 0; j < 16; ++j) v[26+j] = aoo[j];
#pragma unroll
    for (int k = 0; k < 8; ++k)  v[42+k] = sao[k];

    // intra-block additive reduction (waves 1..3 -> wave 0), then global atomics
    __shared__ float red[3][NF][64];
    if (y > 0) {
#pragma unroll
        for (int f = 0; f < NF; ++f) red[y-1][f][m] = v[f];
    }
    __syncthreads();
    if (y == 0) {
#pragma unroll
        for (int f = 0; f < NF; ++f)
            v[f] += red[0][f][m] + red[1][f][m] + red[2][f][m];
        float* acc = ws + WS_ACC;
        int col = (br*B_ + b)*M_ + m;
#pragma unroll
        for (int f = 0; f < NF; ++f)
            unsafeAtomicAdd(acc + f*NCOL + col, v[f]);
    }
}

// ---------------- kernel B: epilogue ----------------
__global__ __launch_bounds__(64) void k_fin(
        const float* __restrict__ W_ope,
        const float* __restrict__ W_arc_in,
        const float* __restrict__ W_arc_out,
        const float* __restrict__ ws,
        float* __restrict__ out) {
    int m = threadIdx.x;         // [0,64)
    int bid = blockIdx.x;        // [0,32)
    int b  = bid & (B_ - 1);
    int br = bid >> 4;
    int col = (br*B_ + b)*M_ + m;

    __shared__ float sW[1024];   // [0..511]=W_ope, [512..767]=W_arc_in, [768..1023]=W_arc_out
    for (int i = m; i < 512; i += 64) sW[i] = W_ope[i];
    for (int i = m; i < 256; i += 64) { sW[512 + i] = W_arc_in[i]; sW[768 + i] = W_arc_out[i]; }
    __syncthreads();

    const float* acc = ws + WS_ACC;
    float v[NF];
#pragma unroll
    for (int f = 0; f < NF; ++f) v[f] = acc[f*NCOL + col];

    const float* pn = ws + WS_PNODE + col*C_;
    float pc[C_];
#pragma unroll
    for (int q = 0; q < 8; ++q) {
        float4 p4 = *(const float4*)(pn + 4*q);
        pc[4*q] = p4.x; pc[4*q+1] = p4.y; pc[4*q+2] = p4.z; pc[4*q+3] = p4.w;
    }

    float en  = ws[WS_ENODE + col];
    float ekk = 2.f*en; ekk = ekk > 0.f ? ekk : SLOPE*ekk;
    float wkk = __expf(ekk);

    float inv_i = 1.f / (v[0]  + wkk);   // l_in  + kk
    float inv_o = 1.f / (v[25] + wkk);   // l_out + kk
    float akk   = wkk*inv_i + wkk*inv_o;

    float* op = out + (size_t)col*C_;
#pragma unroll 4
    for (int c = 0; c < C_; ++c) {
        float s_ai = 0.f, s_oi = 0.f, s_ao = 0.f, s_oo = 0.f;
#pragma unroll
        for (int k = 0; k < 8; ++k) {
            s_ai += v[1+k] *sW[512 + k*C_ + c];   // ai  @ W_arc_in
            s_ao += v[42+k]*sW[768 + k*C_ + c];   // sao @ W_arc_out
        }
#pragma unroll
        for (int j = 0; j < 16; ++j) {
            float wv = sW[j*C_ + c];
            s_oi += v[9+j] *wv;                   // aoi @ W_ope
            s_oo += v[26+j]*wv;                   // aoo @ W_ope
        }
        float x = (s_ai + s_oi)*inv_i + s_ao + s_oo*inv_o + pc[c]*akk;
        op[c] = 1.f/(1.f + __expf(-x));
    }
}

extern "C" void kernel_launch(void* const* d_in, const int* in_sizes, int n_in,
                              void* d_out, int out_size, void* d_ws, size_t ws_size,
                              hipStream_t stream) {
    const float* adj0 = (const float*)d_in[0];
    const float* adj1 = (const float*)d_in[1];
    const float* adj2 = (const float*)d_in[2];
    const float* adj3 = (const float*)d_in[3];
    // d_in[4] = batch_idxes (unused by the reference)
    const float* feat_opes       = (const float*)d_in[5];
    const float* feat_mas        = (const float*)d_in[6];
    const float* feat_buf        = (const float*)d_in[7];
    const float* feat_arc_ma_in  = (const float*)d_in[8];
    const float* feat_arc_buf_in = (const float*)d_in[9];
    const float* feat_arc_ma_out = (const float*)d_in[10];
    const float* feat_arc_buf_out= (const float*)d_in[11];
    const float* W_ope    = (const float*)d_in[12];
    const float* W_mas    = (const float*)d_in[13];
    const float* W_buf    = (const float*)d_in[14];
    const float* W_arc_in = (const float*)d_in[15];
    const float* W_arc_out= (const float*)d_in[16];
    const float* attn_ope = (const float*)d_in[17];
    const float* attn_mas = (const float*)d_in[18];
    const float* attn_arc = (const float*)d_in[19];

    float* ws  = (float*)d_ws;
    float* out = (float*)d_out;

    // 73 precompute blocks + 400 blocks zeroing the ACC region
    k_pre<<<473, 256, 0, stream>>>(feat_opes, feat_mas, feat_buf,
                                   W_ope, W_mas, W_buf, W_arc_in, W_arc_out,
                                   attn_ope, attn_mas, attn_arc, ws);

    k_main<<<2*B_*S_CH, 256, 0, stream>>>(adj0, adj1, adj2, adj3, feat_opes,
                                          feat_arc_ma_in, feat_arc_buf_in,
                                          feat_arc_ma_out, feat_arc_buf_out, ws);

    k_fin<<<2*B_, 64, 0, stream>>>(W_ope, W_arc_in, W_arc_out, ws, out);
}